// Round 4
// baseline (646.868 us; speedup 1.0000x reference)
//
#include <hip/hip_runtime.h>
#include <hip/hip_bf16.h>
#include <stdint.h>

// B=8, Lq=2048, La=2048, H=1024, fp32 in/out.
//   prep:   w -> wTh/wTl (transposed split), q -> qh/ql (split) + qT (bf16 T)
//   stage1: P = q @ w + b          (pure-bf16 3-product MFMA; out = bf16 pair ph/pl)
//   prep:   a -> ah/al (split, reuses qh/ql space)
//   stage2: S^T[a][q] = a . P      (pure-bf16 3-product MFMA, out fp32)
//   softmax over q (rows of S^T), emit bf16 probs in-place
//   stage3: out[a][h] = probs . qT (single-bf16 MFMA)
//
// gemm3s: 256x256 tile, BK=32, 8 waves (2Mx4N), counted-vmcnt 4-phase pipeline.
// All operands bf16 in LDS -> no VALU split in the K-loop (round-3's limiter).

typedef __bf16 bf16x8 __attribute__((ext_vector_type(8)));
typedef float f32x4 __attribute__((ext_vector_type(4)));
typedef unsigned int u32x4 __attribute__((ext_vector_type(4)));
typedef unsigned short ushort_t;

typedef const __attribute__((address_space(1))) void* gas_t;
typedef __attribute__((address_space(3))) void* las_t;

__device__ __forceinline__ void gload_lds16(const void* g, void* l) {
    __builtin_amdgcn_global_load_lds((gas_t)g, (las_t)l, 16, 0, 0);
}

__device__ __forceinline__ unsigned cvt_pk_bf16(float a, float b) {
    unsigned r;
    asm("v_cvt_pk_bf16_f32 %0, %1, %2" : "=v"(r) : "v"(a), "v"(b));
    return r;
}

// split 8 fp32 -> (hi, lo) bf16x8 (RNE two-term split, residual ~2^-16 relative)
__device__ __forceinline__ void split8(f32x4 x0, f32x4 x1, bf16x8& hv, bf16x8& lv) {
    float xs[8];
#pragma unroll
    for (int i = 0; i < 4; ++i) { xs[i] = x0[i]; xs[4 + i] = x1[i]; }
    u32x4 hp, lp;
#pragma unroll
    for (int i = 0; i < 4; ++i) {
        float a = xs[2 * i], b = xs[2 * i + 1];
        unsigned p = cvt_pk_bf16(a, b);
        float ra = __uint_as_float(p << 16);
        float rb = __uint_as_float(p & 0xffff0000u);
        hp[i] = p;
        lp[i] = cvt_pk_bf16(a - ra, b - rb);
    }
    hv = __builtin_bit_cast(bf16x8, hp);
    lv = __builtin_bit_cast(bf16x8, lp);
}

#define MFMA16(a, b, c) __builtin_amdgcn_mfma_f32_16x16x32_bf16(a, b, c, 0, 0, 0)

// ---------------------------------------------------------------------------
// C[M,N] (+bias) = (Ah+Al)[M,K] * (Bh+Bl)[N,K]^T, 3 products (drop lo*lo).
// 256x256 tile, BK=32, 512 threads (2Mx4N waves), per-wave C = 128x64.
// LDS 128KB: 2 x { Ah@0 | Al@16K | Bh@32K | Bl@48K }, each [256][32] bf16.
// Per K-tile t (reads buf[t&1], stages t+1 into buf[(t+1)&1]):
//   P1: read ah[8], bh[4];  stage Ah'; 32 MFMA ah*bh
//   P2: read al[8];         stage Al'; 32 MFMA al*bh
//       s_waitcnt vmcnt(4)  (drains Bl(t); Ah'/Al' may fly)   barrier
//   P3: read bl[4];         stage Bh'; 16 MFMA ah*bl (m0-3)
//   P4:                     stage Bl'; 16 MFMA ah*bl (m4-7)
//       s_waitcnt vmcnt(2)  (drains Ah',Al',Bh'; Bl' flies)   barrier
// Coverage invariant: every LDS region read after a barrier was drained by its
// issuer's vmcnt before that barrier (round-3-proven pattern, streams remapped).
// ---------------------------------------------------------------------------
template<bool BIAS, bool OUTSPLIT>
__global__ __launch_bounds__(512, 1) void gemm3s(
    const ushort_t* __restrict__ Ah, const ushort_t* __restrict__ Al,
    const ushort_t* __restrict__ Bh, const ushort_t* __restrict__ Bl,
    const float* __restrict__ bias,
    float* __restrict__ C, ushort_t* __restrict__ Ph, ushort_t* __restrict__ Pl,
    int lda, int ldb, int ldc, int K, size_t sA, size_t sB, size_t sC)
{
    extern __shared__ char sm[];   // 131072 bytes

    // XCD-bijective swizzle (all grids have (gx*gy) % 8 == 0)
    const int nwg = gridDim.x * gridDim.y;
    int bidl = blockIdx.y * gridDim.x + blockIdx.x;
    bidl = (bidl & 7) * (nwg >> 3) + (bidl >> 3);
    const int bx = bidl % gridDim.x, by = bidl / gridDim.x;
    const int bm = by * 256, bn = bx * 256;

    const ushort_t* Ahg = Ah + (size_t)blockIdx.z * sA;
    const ushort_t* Alg = Al + (size_t)blockIdx.z * sA;
    const ushort_t* Bhg = Bh + (size_t)blockIdx.z * sB;
    const ushort_t* Blg = Bl + (size_t)blockIdx.z * sB;

    const int tid = threadIdx.x, lane = tid & 63, wid = tid >> 6;
    const int wr = wid >> 2, wc = wid & 3;
    const int frow = lane & 15, fkg = lane >> 4;

    // staging constants: bf16 tile [256][32], rows of 64B = 4x16B slots
    const int st_r = wid * 16 + (lane >> 2), st_s = lane & 3;
    const int ldst = wid * 1024 + lane * 16;

    auto stage = [&](const ushort_t* G, int rbase, int ld, int k0, char* dst) {
#pragma unroll
        for (int i = 0; i < 2; ++i) {
            int row = i * 128 + st_r;
            gload_lds16(G + (size_t)(rbase + row) * ld + k0 + ((st_s ^ (row & 3)) << 3),
                        dst + i * 8192 + ldst);
        }
    };

    f32x4 acc[8][4] = {};

    // prologue: tile 0 -> buf0; leave Bl(0) (last 2 loads) outstanding
    stage(Ahg, bm, lda, 0, sm + 0);
    stage(Alg, bm, lda, 0, sm + 16384);
    stage(Bhg, bn, ldb, 0, sm + 32768);
    stage(Blg, bn, ldb, 0, sm + 49152);
    asm volatile("s_waitcnt vmcnt(2)" ::: "memory");
    __builtin_amdgcn_s_barrier();

    const int NT = K >> 5;   // K=1024 -> 32 (power of two)
    for (int t = 0; t < NT; ++t) {
        char* rb = sm + (t & 1) * 65536;
        char* wb = sm + ((t + 1) & 1) * 65536;
        const int kn = ((t + 1) & (NT - 1)) << 5;  // wraps on last tile (benign)

        bf16x8 ah[8], al[8], bh[4], bl[4];

        // ---- P1: ah, bh reads; stage Ah'; ah*bh
#pragma unroll
        for (int m = 0; m < 8; ++m) {
            int r = wr * 128 + m * 16 + frow;
            ah[m] = *(const bf16x8*)(rb + r * 64 + ((fkg ^ (r & 3)) << 4));
        }
#pragma unroll
        for (int n = 0; n < 4; ++n) {
            int r = wc * 64 + n * 16 + frow;
            bh[n] = *(const bf16x8*)(rb + 32768 + r * 64 + ((fkg ^ (r & 3)) << 4));
        }
        stage(Ahg, bm, lda, kn, wb + 0);
        __builtin_amdgcn_s_setprio(1);
#pragma unroll
        for (int m = 0; m < 8; ++m)
#pragma unroll
            for (int n = 0; n < 4; ++n)
                acc[m][n] = MFMA16(ah[m], bh[n], acc[m][n]);
        __builtin_amdgcn_s_setprio(0);

        // ---- P2: al reads; stage Al'; al*bh
#pragma unroll
        for (int m = 0; m < 8; ++m) {
            int r = wr * 128 + m * 16 + frow;
            al[m] = *(const bf16x8*)(rb + 16384 + r * 64 + ((fkg ^ (r & 3)) << 4));
        }
        stage(Alg, bm, lda, kn, wb + 16384);
        __builtin_amdgcn_s_setprio(1);
#pragma unroll
        for (int m = 0; m < 8; ++m)
#pragma unroll
            for (int n = 0; n < 4; ++n)
                acc[m][n] = MFMA16(al[m], bh[n], acc[m][n]);
        __builtin_amdgcn_s_setprio(0);
        asm volatile("s_waitcnt vmcnt(4)" ::: "memory");
        __builtin_amdgcn_s_barrier();

        // ---- P3: bl reads; stage Bh'; ah*bl (m0-3)
#pragma unroll
        for (int n = 0; n < 4; ++n) {
            int r = wc * 64 + n * 16 + frow;
            bl[n] = *(const bf16x8*)(rb + 49152 + r * 64 + ((fkg ^ (r & 3)) << 4));
        }
        stage(Bhg, bn, ldb, kn, wb + 32768);
        __builtin_amdgcn_s_setprio(1);
#pragma unroll
        for (int m = 0; m < 4; ++m)
#pragma unroll
            for (int n = 0; n < 4; ++n)
                acc[m][n] = MFMA16(ah[m], bl[n], acc[m][n]);
        __builtin_amdgcn_s_setprio(0);

        // ---- P4: stage Bl'; ah*bl (m4-7)
        stage(Blg, bn, ldb, kn, wb + 49152);
        __builtin_amdgcn_s_setprio(1);
#pragma unroll
        for (int m = 4; m < 8; ++m)
#pragma unroll
            for (int n = 0; n < 4; ++n)
                acc[m][n] = MFMA16(ah[m], bl[n], acc[m][n]);
        __builtin_amdgcn_s_setprio(0);
        asm volatile("s_waitcnt vmcnt(2)" ::: "memory");
        __builtin_amdgcn_s_barrier();
    }

    // epilogue: C/D layout col=lane&15, row=(lane>>4)*4+j (round-3-verified)
    const size_t zC = (size_t)blockIdx.z * sC;
    const int crow0 = bm + wr * 128 + fkg * 4;
    const int ccol0 = bn + wc * 64 + frow;
#pragma unroll
    for (int n = 0; n < 4; ++n) {
        int col = ccol0 + n * 16;
        float bv = BIAS ? bias[col] : 0.0f;
#pragma unroll
        for (int m = 0; m < 8; ++m)
#pragma unroll
            for (int j = 0; j < 4; ++j) {
                int row = crow0 + m * 16 + j;
                float v = acc[m][n][j] + bv;
                size_t idx = zC + (size_t)row * ldc + col;
                if (OUTSPLIT) {
                    unsigned p = cvt_pk_bf16(v, v);
                    float rh = __uint_as_float(p << 16);
                    unsigned pl2 = cvt_pk_bf16(v - rh, v - rh);
                    Ph[idx] = (ushort_t)(p & 0xffffu);
                    Pl[idx] = (ushort_t)(pl2 & 0xffffu);
                } else {
                    C[idx] = v;
                }
            }
    }
}

// ---------------------------------------------------------------------------
// stage3: C[M,N] = A_bf16[M,K] * B_bf16[N,K]^T  (round-2 kernel, proven)
// ---------------------------------------------------------------------------
__global__ __launch_bounds__(256, 2) void gemm_bf16(
    const ushort_t* __restrict__ A, const ushort_t* __restrict__ B,
    float* __restrict__ C, int lda, int ldb, int ldc, int K,
    size_t sA, size_t sB, size_t sC)
{
    __shared__ char sm[16384];
    const int tid = threadIdx.x;
    const int lane = tid & 63, wid = tid >> 6;
    const int wr = wid >> 1, wc = wid & 1;
    const int bm = blockIdx.y * 128, bn = blockIdx.x * 128;

    const ushort_t* Ag = A + (size_t)blockIdx.z * sA;
    const ushort_t* Bg = B + (size_t)blockIdx.z * sB;

    const int b_rl = lane >> 2, b_s = lane & 3;
    const int b_kslot = b_s ^ (b_rl & 3);
    const int frow = lane & 15, fkg = lane >> 4;

    f32x4 acc[4][4] = {};

    for (int k0 = 0; k0 < K; k0 += 32) {
        __syncthreads();
#pragma unroll
        for (int j = 0; j < 2; ++j) {
            int i = wid * 2 + j;
            int row = i * 16 + b_rl;
            gload_lds16(Ag + (size_t)(bm + row) * lda + (k0 + b_kslot * 8),
                        sm + i * 1024);
            gload_lds16(Bg + (size_t)(bn + row) * ldb + (k0 + b_kslot * 8),
                        sm + 8192 + i * 1024);
        }
        __syncthreads();

        bf16x8 af[4], bf[4];
#pragma unroll
        for (int m = 0; m < 4; ++m) {
            int r = wr * 64 + m * 16 + frow;
            af[m] = *(const bf16x8*)(sm + r * 64 + ((fkg ^ (r & 3)) * 16));
        }
#pragma unroll
        for (int n = 0; n < 4; ++n) {
            int r = wc * 64 + n * 16 + frow;
            bf[n] = *(const bf16x8*)(sm + 8192 + r * 64 + ((fkg ^ (r & 3)) * 16));
        }
#pragma unroll
        for (int m = 0; m < 4; ++m)
#pragma unroll
            for (int n = 0; n < 4; ++n)
                acc[m][n] = MFMA16(af[m], bf[n], acc[m][n]);
    }

    const size_t zC = (size_t)blockIdx.z * sC;
    const int crow0 = bm + wr * 64 + (lane >> 4) * 4;
    const int ccol0 = bn + wc * 64 + (lane & 15);
#pragma unroll
    for (int m = 0; m < 4; ++m)
#pragma unroll
        for (int n = 0; n < 4; ++n)
#pragma unroll
            for (int j = 0; j < 4; ++j)
                C[zC + (size_t)(crow0 + m * 16 + j) * ldc + ccol0 + n * 16] = acc[m][n][j];
}

// ---------------------------------------------------------------------------
// elementwise split: fp32 -> bf16 hi/lo pair (8 elems/thread, fully vectorized)
// ---------------------------------------------------------------------------
__global__ __launch_bounds__(256) void split_pair(const float* __restrict__ in,
                                                  ushort_t* __restrict__ hi,
                                                  ushort_t* __restrict__ lo)
{
    const size_t i = (size_t)blockIdx.x * 256 + threadIdx.x;
    f32x4 x0 = *(const f32x4*)(in + i * 8);
    f32x4 x1 = *(const f32x4*)(in + i * 8 + 4);
    bf16x8 h, l;
    split8(x0, x1, h, l);
    *(bf16x8*)(hi + i * 8) = h;
    *(bf16x8*)(lo + i * 8) = l;
}

// w [1024][1024] fp32 -> wT split (th/tl [n][h] bf16)
__global__ void transpose_split_w(const float* __restrict__ w,
                                  ushort_t* __restrict__ th,
                                  ushort_t* __restrict__ tl)
{
    __shared__ float t[32][33];
    const int bx = blockIdx.x * 32, by = blockIdx.y * 32;
    const int tx = threadIdx.x & 31, ty = threadIdx.x >> 5;
#pragma unroll
    for (int j = 0; j < 4; ++j)
        t[ty + 8 * j][tx] = w[(size_t)(by + ty + 8 * j) * 1024 + bx + tx];
    __syncthreads();
#pragma unroll
    for (int j = 0; j < 4; ++j) {
        float v = t[tx][ty + 8 * j];
        size_t o = (size_t)(bx + ty + 8 * j) * 1024 + by + tx;
        unsigned p = cvt_pk_bf16(v, v);
        float rh = __uint_as_float(p << 16);
        unsigned p2 = cvt_pk_bf16(v - rh, v - rh);
        th[o] = (ushort_t)(p & 0xffffu);
        tl[o] = (ushort_t)(p2 & 0xffffu);
    }
}

// q [B][2048][1024] fp32 -> qT [B][1024][2048] bf16 (single)
__global__ void transpose_q_bf16(const float* __restrict__ q,
                                 ushort_t* __restrict__ qT)
{
    __shared__ float t[32][33];
    const int bx = blockIdx.x * 32, by = blockIdx.y * 32;
    const int tx = threadIdx.x & 31, ty = threadIdx.x >> 5;
    const size_t zin = (size_t)blockIdx.z * 2048 * 1024;
#pragma unroll
    for (int j = 0; j < 4; ++j)
        t[ty + 8 * j][tx] = q[zin + (size_t)(by + ty + 8 * j) * 1024 + bx + tx];
    __syncthreads();
#pragma unroll
    for (int j = 0; j < 4; ++j) {
        float v = t[tx][ty + 8 * j];
        unsigned p = cvt_pk_bf16(v, v);
        qT[zin + (size_t)(bx + ty + 8 * j) * 2048 + by + tx] = (ushort_t)(p & 0xffffu);
    }
}

// ---------------------------------------------------------------------------
// row softmax over 2048 fp32; writes bf16 probs in-place into row start.
// ---------------------------------------------------------------------------
__global__ __launch_bounds__(256) void softmax2048_bf16(float* __restrict__ S, size_t batchStride)
{
    float* row = S + (size_t)blockIdx.y * batchStride + (size_t)blockIdx.x * 2048;
    const int tid = threadIdx.x;
    const int lane = tid & 63, wid = tid >> 6;

    float x[8];
    *(float4*)&x[0] = *(const float4*)(row + tid * 4);
    *(float4*)&x[4] = *(const float4*)(row + 1024 + tid * 4);

    float m = x[0];
#pragma unroll
    for (int i = 1; i < 8; ++i) m = fmaxf(m, x[i]);
#pragma unroll
    for (int o = 1; o < 64; o <<= 1) m = fmaxf(m, __shfl_xor(m, o));

    __shared__ float smax[4], ssum[4];
    if (lane == 0) smax[wid] = m;
    __syncthreads();
    m = fmaxf(fmaxf(smax[0], smax[1]), fmaxf(smax[2], smax[3]));

    float e[8], s = 0.0f;
#pragma unroll
    for (int i = 0; i < 8; ++i) { e[i] = __expf(x[i] - m); s += e[i]; }
#pragma unroll
    for (int o = 1; o < 64; o <<= 1) s += __shfl_xor(s, o);
    if (lane == 0) ssum[wid] = s;
    __syncthreads();
    s = (ssum[0] + ssum[1]) + (ssum[2] + ssum[3]);

    const float inv = 1.0f / s;
    ushort_t* orow = (ushort_t*)row;
    uint2 w0, w1;
    w0.x = cvt_pk_bf16(e[0] * inv, e[1] * inv);
    w0.y = cvt_pk_bf16(e[2] * inv, e[3] * inv);
    w1.x = cvt_pk_bf16(e[4] * inv, e[5] * inv);
    w1.y = cvt_pk_bf16(e[6] * inv, e[7] * inv);
    *(uint2*)(orow + tid * 4) = w0;
    *(uint2*)(orow + 1024 + tid * 4) = w1;
}

// ---------------------------------------------------------------------------
extern "C" void kernel_launch(void* const* d_in, const int* in_sizes, int n_in,
                              void* d_out, int out_size, void* d_ws, size_t ws_size,
                              hipStream_t stream)
{
    const float* q  = (const float*)d_in[0];
    const float* a  = (const float*)d_in[1];
    const float* w  = (const float*)d_in[2];
    const float* bv = (const float*)d_in[3];
    float* out = (float*)d_out;

    const int B = 8, LQ = 2048, LA = 2048, H = 1024;
    const size_t qB = (size_t)LQ * H;          // 2,097,152 elems

    // ws layout (MB): wTh 2 | wTl 2 | qT 32 | ph 32 | pl 32 | sh 32 | sl 32 | S 16*NC
    // sh/sl hold qh/ql for stage1, then ah/al for stage2 (stage1 done first).
    ushort_t* wTh = (ushort_t*)d_ws;
    ushort_t* wTl = wTh + (size_t)H * H;
    ushort_t* qT  = wTl + (size_t)H * H;
    ushort_t* ph  = qT + (size_t)B * H * LQ;
    ushort_t* pl  = ph + (size_t)B * qB;
    ushort_t* sh  = pl + (size_t)B * qB;
    ushort_t* sl  = sh + (size_t)B * qB;
    float* S = (float*)(sl + (size_t)B * qB);

    const size_t baseB = (size_t)(sl + (size_t)B * qB - (ushort_t*)d_ws) * 2;
    const size_t chunkB = (size_t)LA * LQ * 4;   // 16 MB per batch of S
    int NC = 1;
    if (ws_size >= baseB + 4 * chunkB) NC = 4;
    else if (ws_size >= baseB + 2 * chunkB) NC = 2;

    // ---- prep
    transpose_split_w<<<dim3(32, 32), 256, 0, stream>>>(w, wTh, wTl);
    split_pair<<<dim3(8192), 256, 0, stream>>>(q, sh, sl);          // qh, ql
    transpose_q_bf16<<<dim3(32, 64, 8), 256, 0, stream>>>(q, qT);

    // ---- stage1: P = q@w + b  (M=16384, N=1024, K=1024) -> split ph/pl
    gemm3s<true, true><<<dim3(4, 64, 1), 512, 131072, stream>>>(
        sh, sl, wTh, wTl, bv, nullptr, ph, pl, H, H, H, H, 0, 0, 0);

    // ---- split a (reuses sh/sl; stage1 has consumed qh/ql by completion order)
    split_pair<<<dim3(8192), 256, 0, stream>>>(a, sh, sl);          // ah, al

    for (int c0 = 0; c0 < B; c0 += NC) {
        const ushort_t* ahc = sh + (size_t)c0 * qB;
        const ushort_t* alc = sl + (size_t)c0 * qB;
        // stage2: S^T = a . P^T (M=2048, N=2048, K=1024), NC batches
        gemm3s<false, false><<<dim3(8, 8, NC), 512, 131072, stream>>>(
            ahc, alc, ph + (size_t)c0 * qB, pl + (size_t)c0 * qB, nullptr,
            S, nullptr, nullptr,
            H, H, LQ, H, qB, qB, (size_t)LA * LQ);
        softmax2048_bf16<<<dim3(LA, NC), 256, 0, stream>>>(S, (size_t)LA * LQ);
        // stage3: out = probs . qT^T (M=2048, N=1024, K=2048); probs pitch 4096
        gemm_bf16<<<dim3(8, 16, NC), 256, 0, stream>>>(
            (const ushort_t*)S, qT + (size_t)c0 * H * LQ,
            out + (size_t)c0 * LA * H,
            2 * LQ, LQ, H, LQ,
            (size_t)LA * 2 * LQ, (size_t)H * LQ, (size_t)LA * H);
    }
}